// Round 9
// baseline (203.750 us; speedup 1.0000x reference)
//
#include <hip/hip_runtime.h>
#include <math.h>

typedef __attribute__((ext_vector_type(8))) short bf16x8;
typedef __attribute__((ext_vector_type(4))) float f32x4;

constexpr int kN   = 50000;
constexpr int kR   = 8;
constexpr int kIn  = 128;
constexpr int kHid = 128;
constexpr int kOut = 40;
constexpr int kNT  = 16;              // dst nodes per block
constexpr int kLds = 1032;            // ushort row stride (16B-aligned rows)
constexpr float kBnEps = 1e-5f;

// bf16 RNE (prep only, off the critical path)
__device__ inline ushort f2bf(float x) {
    uint u = __float_as_uint(x);
    u += 0x7FFFu + ((u >> 16) & 1u);
    return (ushort)(u >> 16);
}

// ---------------------------------------------------------------------------
// prep: fused  (a) cast x fp32->bf16   [blocks 0..3124, 256 thr x 8 elems]
//              (b) pack W1 into MFMA B-fragment order [blocks 3125..3188]
//              (c) pack W2                            [blocks 3189..3212]
// Fragment f = nt*32 + kt; lane L holds B[n = nt*16 + (L&15)][k = kt*32 + (L>>4)*8 + j].
// ---------------------------------------------------------------------------
__device__ __forceinline__ void pack_unit(const float* __restrict__ W,
                                          ushort* __restrict__ dst,
                                          int N, int frag, int lane)
{
    const int kt = frag & 31;
    const int nt = frag >> 5;
    const int n  = nt * 16 + (lane & 15);
    const int q  = lane >> 4;
    ushort hv[8];
    #pragma unroll
    for (int j = 0; j < 8; ++j) {
        const int k = kt * 32 + q * 8 + j;
        hv[j] = f2bf((n < N) ? W[(size_t)k * N + n] : 0.f);
    }
    const size_t o = ((size_t)frag * 64 + lane) * 8;
    *(ushort4*)&dst[o]     = make_ushort4(hv[0], hv[1], hv[2], hv[3]);
    *(ushort4*)&dst[o + 4] = make_ushort4(hv[4], hv[5], hv[6], hv[7]);
}

__global__ __launch_bounds__(256)
void prep(const float* __restrict__ x,  ushort* __restrict__ xb,
          const float* __restrict__ W1, ushort* __restrict__ W1hi,
          const float* __restrict__ W2, ushort* __restrict__ W2hi)
{
    const int b   = blockIdx.x;
    const int tid = threadIdx.x;
    if (b < 3125) {
        const size_t i = ((size_t)b * 256 + tid) * 8;
        const float4 v0 = *(const float4*)&x[i];
        const float4 v1 = *(const float4*)&x[i + 4];
        *(ushort4*)&xb[i]     = make_ushort4(f2bf(v0.x), f2bf(v0.y), f2bf(v0.z), f2bf(v0.w));
        *(ushort4*)&xb[i + 4] = make_ushort4(f2bf(v1.x), f2bf(v1.y), f2bf(v1.z), f2bf(v1.w));
    } else if (b < 3125 + 64) {
        pack_unit(W1, W1hi, kHid, (b - 3125) * 4 + (tid >> 6), tid & 63);
    } else {
        const int frag = (b - 3189) * 4 + (tid >> 6);
        if (frag < 96) pack_unit(W2, W2hi, kOut, frag, tid & 63);
    }
}

// ---------------------------------------------------------------------------
// Phase A (R6-proven structure): 8 waves x 2 sequential nodes (n = wid, wid+8);
// per-node 16-lane metadata load + readlane; 16 gathers batched; scalar adds.
// Cheap 2-op bf16->f32 convert and 5-op pack/store. No array locals (no scratch).
// ---------------------------------------------------------------------------
#define ACC_ET(ET, BV) {                                                    \
    const float vx = __uint_as_float((BV) << 16);                           \
    const float vy = __uint_as_float((BV) & 0xffff0000u);                   \
    if      ((ET) == 0) { a0.x += vx; a0.y += vy; }                         \
    else if ((ET) == 1) { a1.x += vx; a1.y += vy; }                         \
    else if ((ET) == 2) { a2.x += vx; a2.y += vy; }                         \
    else if ((ET) == 3) { a3.x += vx; a3.y += vy; }                         \
    else if ((ET) == 4) { a4.x += vx; a4.y += vy; }                         \
    else if ((ET) == 5) { a5.x += vx; a5.y += vy; }                         \
    else if ((ET) == 6) { a6.x += vx; a6.y += vy; }                         \
    else                { a7.x += vx; a7.y += vy; } }

#define GATH(BV, S) \
    const uint BV = *(const uint*)(feat + (size_t)(S) * 128 + d2);

#define ACCUM_EDGE(J, BV) \
    { const int et_ = __builtin_amdgcn_readlane(ve, J); ACC_ET(et_, BV) }

#define STORE_AGG(RR, AV) {                                                 \
    const uint px = (__float_as_uint(AV.x) + 0x8000u) >> 16;                \
    const uint py = (__float_as_uint(AV.y) + 0x8000u) & 0xffff0000u;        \
    *(uint*)&aggHi[n][(RR) * 128 + d2] = px | py; }

__device__ __forceinline__ void phaseA_bf16(const ushort* __restrict__ feat,
                                            const int* __restrict__ ptr,
                                            const int* __restrict__ idx,
                                            const int* __restrict__ etype,
                                            int base, ushort (*aggHi)[kLds])
{
    const int lane = threadIdx.x & 63;
    const int wid  = threadIdx.x >> 6;            // 8 waves
    const int d2   = lane * 2;

    #pragma unroll
    for (int t = 0; t < 2; ++t) {
        const int n    = wid + t * 8;
        const int node = base + n;
        const int p0   = ptr[node];
        const int deg  = ptr[node + 1] - p0;

        float2 a0 = {0.f,0.f}, a1 = {0.f,0.f}, a2 = {0.f,0.f}, a3 = {0.f,0.f};
        float2 a4 = {0.f,0.f}, a5 = {0.f,0.f}, a6 = {0.f,0.f}, a7 = {0.f,0.f};

        if (deg == 16) {                          // fixed-degree fast path
            const int vi = idx[p0 + (lane & 15)];
            const int ve = etype[p0 + (lane & 15)];
            const int s0  = __builtin_amdgcn_readlane(vi, 0);
            const int s1  = __builtin_amdgcn_readlane(vi, 1);
            const int s2  = __builtin_amdgcn_readlane(vi, 2);
            const int s3  = __builtin_amdgcn_readlane(vi, 3);
            const int s4  = __builtin_amdgcn_readlane(vi, 4);
            const int s5  = __builtin_amdgcn_readlane(vi, 5);
            const int s6  = __builtin_amdgcn_readlane(vi, 6);
            const int s7  = __builtin_amdgcn_readlane(vi, 7);
            const int s8  = __builtin_amdgcn_readlane(vi, 8);
            const int s9  = __builtin_amdgcn_readlane(vi, 9);
            const int s10 = __builtin_amdgcn_readlane(vi, 10);
            const int s11 = __builtin_amdgcn_readlane(vi, 11);
            const int s12 = __builtin_amdgcn_readlane(vi, 12);
            const int s13 = __builtin_amdgcn_readlane(vi, 13);
            const int s14 = __builtin_amdgcn_readlane(vi, 14);
            const int s15 = __builtin_amdgcn_readlane(vi, 15);
            GATH(b0,  s0)  GATH(b1,  s1)  GATH(b2,  s2)  GATH(b3,  s3)
            GATH(b4,  s4)  GATH(b5,  s5)  GATH(b6,  s6)  GATH(b7,  s7)
            GATH(b8,  s8)  GATH(b9,  s9)  GATH(b10, s10) GATH(b11, s11)
            GATH(b12, s12) GATH(b13, s13) GATH(b14, s14) GATH(b15, s15)
            ACCUM_EDGE(0,  b0)  ACCUM_EDGE(1,  b1)  ACCUM_EDGE(2,  b2)
            ACCUM_EDGE(3,  b3)  ACCUM_EDGE(4,  b4)  ACCUM_EDGE(5,  b5)
            ACCUM_EDGE(6,  b6)  ACCUM_EDGE(7,  b7)  ACCUM_EDGE(8,  b8)
            ACCUM_EDGE(9,  b9)  ACCUM_EDGE(10, b10) ACCUM_EDGE(11, b11)
            ACCUM_EDGE(12, b12) ACCUM_EDGE(13, b13) ACCUM_EDGE(14, b14)
            ACCUM_EDGE(15, b15)
        } else {                                  // generic fallback (never hit)
            for (int e = p0; e < p0 + deg; ++e) {
                const int src = __builtin_amdgcn_readfirstlane(idx[e]);
                const int et_ = __builtin_amdgcn_readfirstlane(etype[e]);
                const uint u  = *(const uint*)(feat + (size_t)src * 128 + d2);
                ACC_ET(et_, u)
            }
        }
        STORE_AGG(0, a0) STORE_AGG(1, a1) STORE_AGG(2, a2) STORE_AGG(3, a3)
        STORE_AGG(4, a4) STORE_AGG(5, a5) STORE_AGG(6, a6) STORE_AGG(7, a7)
    }
}

// ---------------------------------------------------------------------------
// Layer 1: h1 = bf16( relu(bn( (sum_r agg_r @ W1[r]) / deg )) )
// Phase B: explicit software pipeline — B prefetch depth 2 (L2 latency),
// A depth 1 (LDS latency), single accumulator. Named rotation registers
// force the values live across the MFMA (defeats min-pressure scheduling).
// ---------------------------------------------------------------------------
__global__ __launch_bounds__(512, 4)
void rgcn_layer1(const ushort* __restrict__ xb,
                 const ushort* __restrict__ W1hi,
                 const float* __restrict__ gamma, const float* __restrict__ beta,
                 const float* __restrict__ mean,  const float* __restrict__ var,
                 const int* __restrict__ ptr, const int* __restrict__ idx,
                 const int* __restrict__ etype,
                 ushort* __restrict__ h1b)
{
    __shared__ ushort aggHi[kNT][kLds];           // 33 KB
    const int tid  = threadIdx.x;
    const int base = blockIdx.x * kNT;

    phaseA_bf16(xb, ptr, idx, etype, base, aggHi);
    __syncthreads();

    const int lane = tid & 63;
    const int wid  = tid >> 6;                    // n-tile owned by this wave
    const int m    = lane & 15;
    const int q    = lane >> 4;

    const bf16x8* Bh = (const bf16x8*)W1hi + (size_t)wid * 32 * 64 + lane;
    bf16x8 bc = Bh[0];                            // B frag kt
    bf16x8 bn = Bh[64];                           // B frag kt+1
    bf16x8 ac = *(const bf16x8*)&aggHi[m][q * 8]; // A frag kt
    f32x4 acc = {0.f, 0.f, 0.f, 0.f};

    #pragma unroll
    for (int kt = 0; kt < 32; ++kt) {
        const int ktb = (kt + 2 < 32) ? kt + 2 : 0;
        const int kta = (kt + 1 < 32) ? kt + 1 : 0;
        const bf16x8 bf_ = Bh[(size_t)ktb * 64];
        const bf16x8 af_ = *(const bf16x8*)&aggHi[m][kta * 32 + q * 8];
        acc = __builtin_amdgcn_mfma_f32_16x16x32_bf16(ac, bc, acc, 0, 0, 0);
        ac = af_; bc = bn; bn = bf_;
    }

    // Epilogue: deg norm + BN + ReLU, write bf16 h1
    const int c = wid * 16 + m;
    const float g  = gamma[c] * rsqrtf(var[c] + kBnEps);
    const float mu = mean[c];
    const float bt = beta[c];
    #pragma unroll
    for (int i = 0; i < 4; ++i) {
        const int node = base + q * 4 + i;
        const float invdeg = 1.0f / (float)(ptr[node + 1] - ptr[node]);
        float v = (acc[i] * invdeg - mu) * g + bt;
        v = fmaxf(v, 0.f);
        h1b[(size_t)node * kHid + c] = (ushort)((__float_as_uint(v) + 0x8000u) >> 16);
    }
}

// ---------------------------------------------------------------------------
// Layer 2: out = log_softmax( (sum_r agg_r @ W2[r]) / deg ), N padded 40->48
// ---------------------------------------------------------------------------
__global__ __launch_bounds__(512, 4)
void rgcn_layer2(const ushort* __restrict__ h1b,
                 const ushort* __restrict__ W2hi,
                 const int* __restrict__ ptr, const int* __restrict__ idx,
                 const int* __restrict__ etype,
                 float* __restrict__ out)
{
    __shared__ ushort aggHi[kNT][kLds];           // 33 KB
    __shared__ float logits[kNT][48];             // 3 KB
    const int tid  = threadIdx.x;
    const int base = blockIdx.x * kNT;

    phaseA_bf16(h1b, ptr, idx, etype, base, aggHi);
    __syncthreads();

    const int lane = tid & 63;
    const int wid  = tid >> 6;
    const int m    = lane & 15;
    const int q    = lane >> 4;

    if (wid < 3) {                                // n-tiles 0..2 cover 48 cols
        const bf16x8* Bh = (const bf16x8*)W2hi + (size_t)wid * 32 * 64 + lane;
        bf16x8 bc = Bh[0];
        bf16x8 bn = Bh[64];
        bf16x8 ac = *(const bf16x8*)&aggHi[m][q * 8];
        f32x4 acc = {0.f, 0.f, 0.f, 0.f};
        #pragma unroll
        for (int kt = 0; kt < 32; ++kt) {
            const int ktb = (kt + 2 < 32) ? kt + 2 : 0;
            const int kta = (kt + 1 < 32) ? kt + 1 : 0;
            const bf16x8 bf_ = Bh[(size_t)ktb * 64];
            const bf16x8 af_ = *(const bf16x8*)&aggHi[m][kta * 32 + q * 8];
            acc = __builtin_amdgcn_mfma_f32_16x16x32_bf16(ac, bc, acc, 0, 0, 0);
            ac = af_; bc = bn; bn = bf_;
        }
        const int n = wid * 16 + m;               // logit column
        if (n < kOut) {
            #pragma unroll
            for (int i = 0; i < 4; ++i) {
                const int node = base + q * 4 + i;
                const float invdeg = 1.0f / (float)(ptr[node + 1] - ptr[node]);
                logits[q * 4 + i][n] = acc[i] * invdeg;
            }
        }
    }
    __syncthreads();

    // log_softmax: wave w handles nodes w*2, w*2+1
    #pragma unroll
    for (int i = 0; i < 2; ++i) {
        const int nrow = wid * 2 + i;
        const int node = base + nrow;
        const float v = (lane < kOut) ? logits[nrow][lane] : -INFINITY;
        float mx = v;
        #pragma unroll
        for (int off = 32; off > 0; off >>= 1)
            mx = fmaxf(mx, __shfl_xor(mx, off, 64));
        float s = (lane < kOut) ? __expf(v - mx) : 0.f;
        #pragma unroll
        for (int off = 32; off > 0; off >>= 1)
            s += __shfl_xor(s, off, 64);
        if (lane < kOut)
            out[(size_t)node * kOut + lane] = v - mx - __logf(s);
    }
}

// ---------------------------------------------------------------------------
extern "C" void kernel_launch(void* const* d_in, const int* in_sizes, int n_in,
                              void* d_out, int out_size, void* d_ws, size_t ws_size,
                              hipStream_t stream)
{
    const float* x     = (const float*)d_in[0];
    const float* W1    = (const float*)d_in[1];
    const float* W2    = (const float*)d_in[2];
    const float* gamma = (const float*)d_in[3];
    const float* beta  = (const float*)d_in[4];
    const float* mean  = (const float*)d_in[5];
    const float* var   = (const float*)d_in[6];
    const int*   ptr   = (const int*)d_in[7];
    const int*   idx   = (const int*)d_in[8];
    const int*   et    = (const int*)d_in[9];
    float*       out   = (float*)d_out;

    // Workspace (~26 MB)
    char* ws = (char*)d_ws;
    ushort* h1b  = (ushort*)ws;                              // 12,800,000 B
    ushort* xb   = (ushort*)(ws + 12800000);                 // 12,800,000 B
    ushort* W1hi = (ushort*)(ws + 25600000);                 //    262,144 B
    ushort* W2hi = (ushort*)(ws + 25600000 + 262144);        //     98,304 B

    prep<<<dim3(3125 + 64 + 24), dim3(256), 0, stream>>>(x, xb, W1, W1hi, W2, W2hi);

    dim3 grid(kN / kNT), block(512);
    rgcn_layer1<<<grid, block, 0, stream>>>(xb, W1hi, gamma, beta, mean, var,
                                            ptr, idx, et, h1b);
    rgcn_layer2<<<grid, block, 0, stream>>>(h1b, W2hi, ptr, idx, et, out);
}

// Round 10
// 194.136 us; speedup vs baseline: 1.0495x; 1.0495x over previous
//
#include <hip/hip_runtime.h>
#include <math.h>

typedef __attribute__((ext_vector_type(8))) short bf16x8;
typedef __attribute__((ext_vector_type(4))) float f32x4;

constexpr int kN   = 50000;
constexpr int kR   = 8;
constexpr int kIn  = 128;
constexpr int kHid = 128;
constexpr int kOut = 40;
constexpr int kNT  = 16;              // dst nodes per block
constexpr int kLds = 1032;            // ushort row stride (16B-aligned rows)
constexpr float kBnEps = 1e-5f;

// bf16 helpers (RNE)
__device__ inline ushort f2bf(float x) {
    uint u = __float_as_uint(x);
    u += 0x7FFFu + ((u >> 16) & 1u);
    return (ushort)(u >> 16);
}
__device__ inline float bf2f(ushort s) { return __uint_as_float(((uint)s) << 16); }

// ---------------------------------------------------------------------------
// prep: fused  (a) cast x fp32->bf16   [blocks 0..3124, 256 thr x 8 elems]
//              (b) pack W1 into MFMA B-fragment order [blocks 3125..3188]
//              (c) pack W2                            [blocks 3189..3212]
// Fragment f = nt*32 + kt; lane L holds B[n = nt*16 + (L&15)][k = kt*32 + (L>>4)*8 + j].
// ---------------------------------------------------------------------------
__device__ __forceinline__ void pack_unit(const float* __restrict__ W,
                                          ushort* __restrict__ dst,
                                          int N, int frag, int lane)
{
    const int kt = frag & 31;
    const int nt = frag >> 5;
    const int n  = nt * 16 + (lane & 15);
    const int q  = lane >> 4;
    ushort hv[8];
    #pragma unroll
    for (int j = 0; j < 8; ++j) {
        const int k = kt * 32 + q * 8 + j;
        hv[j] = f2bf((n < N) ? W[(size_t)k * N + n] : 0.f);
    }
    const size_t o = ((size_t)frag * 64 + lane) * 8;
    *(ushort4*)&dst[o]     = make_ushort4(hv[0], hv[1], hv[2], hv[3]);
    *(ushort4*)&dst[o + 4] = make_ushort4(hv[4], hv[5], hv[6], hv[7]);
}

__global__ __launch_bounds__(256)
void prep(const float* __restrict__ x,  ushort* __restrict__ xb,
          const float* __restrict__ W1, ushort* __restrict__ W1hi,
          const float* __restrict__ W2, ushort* __restrict__ W2hi)
{
    const int b   = blockIdx.x;
    const int tid = threadIdx.x;
    if (b < 3125) {
        const size_t i = ((size_t)b * 256 + tid) * 8;
        const float4 v0 = *(const float4*)&x[i];
        const float4 v1 = *(const float4*)&x[i + 4];
        *(ushort4*)&xb[i]     = make_ushort4(f2bf(v0.x), f2bf(v0.y), f2bf(v0.z), f2bf(v0.w));
        *(ushort4*)&xb[i + 4] = make_ushort4(f2bf(v1.x), f2bf(v1.y), f2bf(v1.z), f2bf(v1.w));
    } else if (b < 3125 + 64) {
        pack_unit(W1, W1hi, kHid, (b - 3125) * 4 + (tid >> 6), tid & 63);
    } else {
        const int frag = (b - 3189) * 4 + (tid >> 6);
        if (frag < 96) pack_unit(W2, W2hi, kOut, frag, tid & 63);
    }
}

// ---------------------------------------------------------------------------
// Phase A (R6-proven, verbatim): NO private arrays (named scalars only).
// 8 waves x 2 sequential nodes; lane owns bf16 pair d = lane*2, lane*2+1.
// All 16 gathers issued back-to-back, then wave-uniform branchy accumulate.
// ---------------------------------------------------------------------------
#define ACCUM_ET(ET, VX, VY)                                   \
    if      ((ET) == 0) { a0.x += (VX); a0.y += (VY); }        \
    else if ((ET) == 1) { a1.x += (VX); a1.y += (VY); }        \
    else if ((ET) == 2) { a2.x += (VX); a2.y += (VY); }        \
    else if ((ET) == 3) { a3.x += (VX); a3.y += (VY); }        \
    else if ((ET) == 4) { a4.x += (VX); a4.y += (VY); }        \
    else if ((ET) == 5) { a5.x += (VX); a5.y += (VY); }        \
    else if ((ET) == 6) { a6.x += (VX); a6.y += (VY); }        \
    else                { a7.x += (VX); a7.y += (VY); }

#define GATHER(BV, SRC) \
    const ushort2 BV = *(const ushort2*)&feat[(size_t)(SRC) * 128 + d2];

#define ACCUM_EDGE(J, BV) \
    { const int et = __builtin_amdgcn_readlane(ve, J); ACCUM_ET(et, bf2f(BV.x), bf2f(BV.y)) }

#define STORE_AGG(RR, AV) \
    *(ushort2*)&aggHi[n][(RR) * 128 + d2] = make_ushort2(f2bf(AV.x), f2bf(AV.y));

__device__ __forceinline__ void phaseA_bf16(const ushort* __restrict__ feat,
                                            const int* __restrict__ ptr,
                                            const int* __restrict__ idx,
                                            const int* __restrict__ etype,
                                            int base, ushort (*aggHi)[kLds])
{
    const int lane = threadIdx.x & 63;
    const int wid  = threadIdx.x >> 6;            // 8 waves
    const int d2   = lane * 2;

    #pragma unroll
    for (int t = 0; t < 2; ++t) {
        const int n    = wid * 2 + t;
        const int node = base + n;
        const int p0   = ptr[node];
        const int deg  = ptr[node + 1] - p0;

        float2 a0 = {0.f,0.f}, a1 = {0.f,0.f}, a2 = {0.f,0.f}, a3 = {0.f,0.f};
        float2 a4 = {0.f,0.f}, a5 = {0.f,0.f}, a6 = {0.f,0.f}, a7 = {0.f,0.f};

        if (deg == 16) {                          // fixed-degree fast path
            const int vi = idx[p0 + (lane & 15)];
            const int ve = etype[p0 + (lane & 15)];
            const int s0  = __builtin_amdgcn_readlane(vi, 0);
            const int s1  = __builtin_amdgcn_readlane(vi, 1);
            const int s2  = __builtin_amdgcn_readlane(vi, 2);
            const int s3  = __builtin_amdgcn_readlane(vi, 3);
            const int s4  = __builtin_amdgcn_readlane(vi, 4);
            const int s5  = __builtin_amdgcn_readlane(vi, 5);
            const int s6  = __builtin_amdgcn_readlane(vi, 6);
            const int s7  = __builtin_amdgcn_readlane(vi, 7);
            const int s8  = __builtin_amdgcn_readlane(vi, 8);
            const int s9  = __builtin_amdgcn_readlane(vi, 9);
            const int s10 = __builtin_amdgcn_readlane(vi, 10);
            const int s11 = __builtin_amdgcn_readlane(vi, 11);
            const int s12 = __builtin_amdgcn_readlane(vi, 12);
            const int s13 = __builtin_amdgcn_readlane(vi, 13);
            const int s14 = __builtin_amdgcn_readlane(vi, 14);
            const int s15 = __builtin_amdgcn_readlane(vi, 15);
            GATHER(b0,  s0)  GATHER(b1,  s1)  GATHER(b2,  s2)  GATHER(b3,  s3)
            GATHER(b4,  s4)  GATHER(b5,  s5)  GATHER(b6,  s6)  GATHER(b7,  s7)
            GATHER(b8,  s8)  GATHER(b9,  s9)  GATHER(b10, s10) GATHER(b11, s11)
            GATHER(b12, s12) GATHER(b13, s13) GATHER(b14, s14) GATHER(b15, s15)
            ACCUM_EDGE(0,  b0)  ACCUM_EDGE(1,  b1)  ACCUM_EDGE(2,  b2)  ACCUM_EDGE(3,  b3)
            ACCUM_EDGE(4,  b4)  ACCUM_EDGE(5,  b5)  ACCUM_EDGE(6,  b6)  ACCUM_EDGE(7,  b7)
            ACCUM_EDGE(8,  b8)  ACCUM_EDGE(9,  b9)  ACCUM_EDGE(10, b10) ACCUM_EDGE(11, b11)
            ACCUM_EDGE(12, b12) ACCUM_EDGE(13, b13) ACCUM_EDGE(14, b14) ACCUM_EDGE(15, b15)
        } else {                                  // generic fallback (never hit)
            for (int e = p0; e < p0 + deg; ++e) {
                const int src = __builtin_amdgcn_readfirstlane(idx[e]);
                const int et  = __builtin_amdgcn_readfirstlane(etype[e]);
                const ushort2 u = *(const ushort2*)&feat[(size_t)src * 128 + d2];
                ACCUM_ET(et, bf2f(u.x), bf2f(u.y))
            }
        }
        STORE_AGG(0, a0) STORE_AGG(1, a1) STORE_AGG(2, a2) STORE_AGG(3, a3)
        STORE_AGG(4, a4) STORE_AGG(5, a5) STORE_AGG(6, a6) STORE_AGG(7, a7)
    }
}

// ---------------------------------------------------------------------------
// Layer 1: h1 = bf16( relu(bn( (sum_r agg_r @ W1[r]) / deg )) )
// Phase B (R6-proven): single accumulator, kt++, unroll 4.
// ---------------------------------------------------------------------------
__global__ __launch_bounds__(512, 4)
void rgcn_layer1(const ushort* __restrict__ xb,
                 const ushort* __restrict__ W1hi,
                 const float* __restrict__ gamma, const float* __restrict__ beta,
                 const float* __restrict__ mean,  const float* __restrict__ var,
                 const int* __restrict__ ptr, const int* __restrict__ idx,
                 const int* __restrict__ etype,
                 ushort* __restrict__ h1b)
{
    __shared__ ushort aggHi[kNT][kLds];           // 33 KB
    const int tid  = threadIdx.x;
    const int base = blockIdx.x * kNT;

    phaseA_bf16(xb, ptr, idx, etype, base, aggHi);
    __syncthreads();

    const int lane = tid & 63;
    const int wid  = tid >> 6;                    // n-tile owned by this wave
    const int m    = lane & 15;
    const int q    = lane >> 4;

    const bf16x8* Bh = (const bf16x8*)W1hi + (size_t)wid * 32 * 64 + lane;
    f32x4 acc = {0.f, 0.f, 0.f, 0.f};

    #pragma unroll 4
    for (int kt = 0; kt < 32; ++kt) {
        const bf16x8 ah = *(const bf16x8*)&aggHi[m][kt * 32 + q * 8];
        const bf16x8 bh = Bh[(size_t)kt * 64];
        acc = __builtin_amdgcn_mfma_f32_16x16x32_bf16(ah, bh, acc, 0, 0, 0);
    }

    // Epilogue: deg norm + BN + ReLU, write bf16 h1
    const int c = wid * 16 + m;
    const float g  = gamma[c] * rsqrtf(var[c] + kBnEps);
    const float mu = mean[c];
    const float bt = beta[c];
    #pragma unroll
    for (int i = 0; i < 4; ++i) {
        const int node = base + q * 4 + i;
        const float invdeg = 1.0f / (float)(ptr[node + 1] - ptr[node]);
        float v = (acc[i] * invdeg - mu) * g + bt;
        v = fmaxf(v, 0.f);
        h1b[(size_t)node * kHid + c] = f2bf(v);
    }
}

// ---------------------------------------------------------------------------
// Layer 2: out = log_softmax( (sum_r agg_r @ W2[r]) / deg ), N padded 40->48
// ---------------------------------------------------------------------------
__global__ __launch_bounds__(512, 4)
void rgcn_layer2(const ushort* __restrict__ h1b,
                 const ushort* __restrict__ W2hi,
                 const int* __restrict__ ptr, const int* __restrict__ idx,
                 const int* __restrict__ etype,
                 float* __restrict__ out)
{
    __shared__ ushort aggHi[kNT][kLds];           // 33 KB
    __shared__ float logits[kNT][48];             // 3 KB
    const int tid  = threadIdx.x;
    const int base = blockIdx.x * kNT;

    phaseA_bf16(h1b, ptr, idx, etype, base, aggHi);
    __syncthreads();

    const int lane = tid & 63;
    const int wid  = tid >> 6;
    const int m    = lane & 15;
    const int q    = lane >> 4;

    if (wid < 3) {                                // n-tiles 0..2 cover 48 cols
        const bf16x8* Bh = (const bf16x8*)W2hi + (size_t)wid * 32 * 64 + lane;
        f32x4 acc = {0.f, 0.f, 0.f, 0.f};
        #pragma unroll 4
        for (int kt = 0; kt < 32; ++kt) {
            const bf16x8 ah = *(const bf16x8*)&aggHi[m][kt * 32 + q * 8];
            const bf16x8 bh = Bh[(size_t)kt * 64];
            acc = __builtin_amdgcn_mfma_f32_16x16x32_bf16(ah, bh, acc, 0, 0, 0);
        }
        const int n = wid * 16 + m;               // logit column
        if (n < kOut) {
            #pragma unroll
            for (int i = 0; i < 4; ++i) {
                const int node = base + q * 4 + i;
                const float invdeg = 1.0f / (float)(ptr[node + 1] - ptr[node]);
                logits[q * 4 + i][n] = acc[i] * invdeg;
            }
        }
    }
    __syncthreads();

    // log_softmax: wave w handles nodes w*2, w*2+1
    #pragma unroll
    for (int i = 0; i < 2; ++i) {
        const int nrow = wid * 2 + i;
        const int node = base + nrow;
        const float v = (lane < kOut) ? logits[nrow][lane] : -INFINITY;
        float mx = v;
        #pragma unroll
        for (int off = 32; off > 0; off >>= 1)
            mx = fmaxf(mx, __shfl_xor(mx, off, 64));
        float s = (lane < kOut) ? __expf(v - mx) : 0.f;
        #pragma unroll
        for (int off = 32; off > 0; off >>= 1)
            s += __shfl_xor(s, off, 64);
        if (lane < kOut)
            out[(size_t)node * kOut + lane] = v - mx - __logf(s);
    }
}

// ---------------------------------------------------------------------------
extern "C" void kernel_launch(void* const* d_in, const int* in_sizes, int n_in,
                              void* d_out, int out_size, void* d_ws, size_t ws_size,
                              hipStream_t stream)
{
    const float* x     = (const float*)d_in[0];
    const float* W1    = (const float*)d_in[1];
    const float* W2    = (const float*)d_in[2];
    const float* gamma = (const float*)d_in[3];
    const float* beta  = (const float*)d_in[4];
    const float* mean  = (const float*)d_in[5];
    const float* var   = (const float*)d_in[6];
    const int*   ptr   = (const int*)d_in[7];
    const int*   idx   = (const int*)d_in[8];
    const int*   et    = (const int*)d_in[9];
    float*       out   = (float*)d_out;

    // Workspace (~26 MB)
    char* ws = (char*)d_ws;
    ushort* h1b  = (ushort*)ws;                              // 12,800,000 B
    ushort* xb   = (ushort*)(ws + 12800000);                 // 12,800,000 B
    ushort* W1hi = (ushort*)(ws + 25600000);                 //    262,144 B
    ushort* W2hi = (ushort*)(ws + 25600000 + 262144);        //     98,304 B

    prep<<<dim3(3125 + 64 + 24), dim3(256), 0, stream>>>(x, xb, W1, W1hi, W2, W2hi);

    dim3 grid(kN / kNT), block(512);
    rgcn_layer1<<<grid, block, 0, stream>>>(xb, W1hi, gamma, beta, mean, var,
                                            ptr, idx, et, h1b);
    rgcn_layer2<<<grid, block, 0, stream>>>(h1b, W2hi, ptr, idx, et, out);
}